// Round 1
// baseline (340.326 us; speedup 1.0000x reference)
//
#include <hip/hip_runtime.h>
#include <cmath>

typedef __bf16 bf16_t;
typedef __attribute__((ext_vector_type(8))) __bf16 bf16x8;
typedef __attribute__((ext_vector_type(4))) __bf16 bf16x4;
typedef __attribute__((ext_vector_type(4))) float f32x4;

#define RMS_EPS 1.1920929e-07f
#define KV_SCALE 0.04419417382415922f   // 1/sqrt(512)

__device__ __forceinline__ void gload16(const void* g, void* l) {
  __builtin_amdgcn_global_load_lds((const __attribute__((address_space(1))) void*)g,
                                   (__attribute__((address_space(3))) void*)l, 16, 0, 0);
}

__device__ __forceinline__ float eluf(float x) { return x > 0.f ? x : expm1f(x); }

// ---------- fp32 -> bf16 cast, exactly 1M elements: grid 1024 x 256 ----------
__global__ __launch_bounds__(256) void cast_bf16_1m(const float* __restrict__ s,
                                                    bf16_t* __restrict__ d) {
  int i = (blockIdx.x * 256 + threadIdx.x) * 4;
  float4 v = *(const float4*)(s + i);
  bf16x4 o;
  o[0] = (bf16_t)v.x; o[1] = (bf16_t)v.y; o[2] = (bf16_t)v.z; o[3] = (bf16_t)v.w;
  *(bf16x4*)(d + i) = o;
}

__global__ void concat_bias(const float* __restrict__ bq, const float* __restrict__ bk,
                            const float* __restrict__ bv, float* __restrict__ dst) {
  int i = blockIdx.x * 256 + threadIdx.x;   // grid 12*256 = 3072
  float v;
  if (i < 1024) v = bq[i];
  else if (i < 2048) v = bk[i - 1024];
  else v = bv[i - 2048];
  dst[i] = v;
}

// ---------- RMSNorm(x, g1) -> bf16, one block per row of 1024 ----------
__global__ __launch_bounds__(256) void rmsnorm_x(const float* __restrict__ x,
                                                 const float* __restrict__ g,
                                                 bf16_t* __restrict__ xn) {
  const int m = blockIdx.x, t = threadIdx.x;
  const float4 v = ((const float4*)(x + (size_t)m * 1024))[t];
  float ss = v.x * v.x + v.y * v.y + v.z * v.z + v.w * v.w;
  #pragma unroll
  for (int o = 1; o < 64; o <<= 1) ss += __shfl_xor(ss, o);
  __shared__ float red[4];
  if ((t & 63) == 0) red[t >> 6] = ss;
  __syncthreads();
  const float r = rsqrtf((red[0] + red[1] + red[2] + red[3]) * (1.f / 1024.f) + RMS_EPS);
  const float4 gv = ((const float4*)g)[t];
  bf16x4 o;
  o[0] = (bf16_t)(v.x * r * gv.x); o[1] = (bf16_t)(v.y * r * gv.y);
  o[2] = (bf16_t)(v.z * r * gv.z); o[3] = (bf16_t)(v.w * r * gv.w);
  *(bf16x4*)(xn + (size_t)m * 1024 + t * 4) = o;
}

// ---------- NT GEMM: C[m,n] = sum_k A[m,k]*B[n,k], m97 structure ----------
// MODE 0: +bias -> bf16 out     (QKV, N=3072)
// MODE 1: +bias -> gelu -> bf16 (FFN1, N=1024)
// MODE 2: +bias +resid -> f32   (FFN2, N=1024)
template <int MODE>
__global__ __launch_bounds__(256) void gemm_nt(const bf16_t* __restrict__ A,
                                               const bf16_t* __restrict__ Bm,
                                               const float* __restrict__ bias,
                                               const float* __restrict__ resid,
                                               void* __restrict__ outp,
                                               int M, int N, int K) {
  __shared__ bf16_t As[128][32];
  __shared__ bf16_t Bs[128][32];
  const int t = threadIdx.x;
  const int lane = t & 63;
  const int w = t >> 6;
  const int wm = w >> 1, wn = w & 1;
  const int nTN = N >> 7;

  // bijective XCD swizzle (nwg % 8 == 0 for all our grids)
  const int nwg = gridDim.x;
  const int cpx = nwg >> 3;
  int bid = blockIdx.x;
  bid = (bid & 7) * cpx + (bid >> 3);
  const int tm = bid / nTN, tn = bid % nTN;

  const size_t rowA = (size_t)tm * 128;
  const size_t rowB = (size_t)tn * 128;
  const size_t sK = (size_t)K;

  f32x4 acc[4][4];
  #pragma unroll
  for (int i = 0; i < 4; ++i)
    #pragma unroll
    for (int j = 0; j < 4; ++j) acc[i][j] = (f32x4){0.f, 0.f, 0.f, 0.f};

  const int sr = lane >> 2;          // staging row within 16-row group
  const int sc = (lane & 3) << 3;    // staging col (elements)
  const int r16 = lane & 15;
  const int c8 = (lane >> 4) << 3;

  for (int k0 = 0; k0 < K; k0 += 32) {
    // stage A,B tiles (128x32 bf16 each) via direct-to-LDS, linear dest
    gload16(A  + (rowA +      w * 16 + sr) * sK + (k0 + sc), &As[w * 16][0]);
    gload16(A  + (rowA + 64 + w * 16 + sr) * sK + (k0 + sc), &As[64 + w * 16][0]);
    gload16(Bm + (rowB +      w * 16 + sr) * sK + (k0 + sc), &Bs[w * 16][0]);
    gload16(Bm + (rowB + 64 + w * 16 + sr) * sK + (k0 + sc), &Bs[64 + w * 16][0]);
    __syncthreads();

    bf16x8 a[4], b[4];
    #pragma unroll
    for (int i = 0; i < 4; ++i) {
      a[i] = *(const bf16x8*)&As[wm * 64 + i * 16 + r16][c8];
      b[i] = *(const bf16x8*)&Bs[wn * 64 + i * 16 + r16][c8];
    }
    #pragma unroll
    for (int i = 0; i < 4; ++i)
      #pragma unroll
      for (int j = 0; j < 4; ++j)
        acc[i][j] = __builtin_amdgcn_mfma_f32_16x16x32_bf16(a[i], b[j], acc[i][j], 0, 0, 0);
    __syncthreads();
  }

  // epilogue: C/D layout col = lane&15, row = (lane>>4)*4 + reg
  const int hi4 = (lane >> 4) * 4;
  #pragma unroll
  for (int i = 0; i < 4; ++i) {
    #pragma unroll
    for (int j = 0; j < 4; ++j) {
      const int gc = tn * 128 + wn * 64 + j * 16 + r16;
      const float bv = bias[gc];
      #pragma unroll
      for (int r = 0; r < 4; ++r) {
        const int gr = tm * 128 + wm * 64 + i * 16 + hi4 + r;
        float v = acc[i][j][r] + bv;
        if constexpr (MODE == 0) {
          ((bf16_t*)outp)[(size_t)gr * N + gc] = (bf16_t)v;
        } else if constexpr (MODE == 1) {
          v = 0.5f * v * (1.0f + erff(v * 0.70710678118654752f));
          ((bf16_t*)outp)[(size_t)gr * N + gc] = (bf16_t)v;
        } else {
          v += resid[(size_t)gr * N + gc];
          ((float*)outp)[(size_t)gr * N + gc] = v;
        }
      }
    }
  }
}

// ---------- per-position differential linear attention + norms ----------
__global__ __launch_bounds__(256) void attn_pos(const bf16_t* __restrict__ qkv,
                                                const float* __restrict__ lp,
                                                const float* __restrict__ g2,
                                                const float* __restrict__ g3,
                                                float* __restrict__ attnf,
                                                bf16_t* __restrict__ attnb) {
  const int m = blockIdx.x;
  const int t = threadIdx.x;
  const int lane = t & 63;
  const int w = t >> 6;
  __shared__ float sQ[16][64], sKm[16][64], sV[16][64];
  __shared__ float sKV[64][64];
  __shared__ float red[4];

  const bf16x4* row4 = (const bf16x4*)(qkv + (size_t)m * 3072);
  #pragma unroll
  for (int c = 0; c < 3; ++c) {
    const int idx = t + c * 256;
    bf16x4 u = row4[idx];
    float f0 = (float)u[0], f1 = (float)u[1], f2 = (float)u[2], f3 = (float)u[3];
    int e0 = idx * 4;
    if (e0 < 1024) {
      int r = e0 >> 6, cc = e0 & 63;
      sQ[r][cc] = eluf(f0); sQ[r][cc + 1] = eluf(f1); sQ[r][cc + 2] = eluf(f2); sQ[r][cc + 3] = eluf(f3);
    } else if (e0 < 2048) {
      int e = e0 - 1024, r = e >> 6, cc = e & 63;
      sKm[r][cc] = eluf(f0); sKm[r][cc + 1] = eluf(f1); sKm[r][cc + 2] = eluf(f2); sKm[r][cc + 3] = eluf(f3);
    } else {
      int e = e0 - 2048, r = e >> 6, cc = e & 63;
      sV[r][cc] = f0; sV[r][cc + 1] = f1; sV[r][cc + 2] = f2; sV[r][cc + 3] = f3;
    }
  }
  const float lmbda = expf(lp[0] * lp[1]) - expf(lp[2] * lp[3]) + 0.2f;
  __syncthreads();

  const int e = lane;
  // kv[d][e] = SCALE * sum_h phiK[h][d] * V[h][e]; fold -lambda into d>=32 half
  float vreg[16];
  #pragma unroll
  for (int h = 0; h < 16; ++h) vreg[h] = sV[h][e];
  #pragma unroll
  for (int i = 0; i < 16; ++i) {
    const int d = w * 16 + i;
    float a = 0.f;
    #pragma unroll
    for (int h = 0; h < 16; ++h) a += sKm[h][d] * vreg[h];
    sKV[d][e] = a * ((d < 32) ? KV_SCALE : -lmbda * KV_SCALE);
  }
  __syncthreads();

  // attn[h][e] = sum_d phiQ[h][d] * kv'[d][e], 4 h-rows per thread
  float a0 = 0.f, a1 = 0.f, a2 = 0.f, a3 = 0.f;
  #pragma unroll
  for (int d = 0; d < 64; ++d) {
    const float kvv = sKV[d][e];
    a0 += sQ[w][d] * kvv;
    a1 += sQ[w + 4][d] * kvv;
    a2 += sQ[w + 8][d] * kvv;
    a3 += sQ[w + 12][d] * kvv;
  }
  float val[4] = {a0, a1, a2, a3};

  // group rmsnorm over e (full wave = 64 lanes = the DH axis), * g2 * (1-0.2)
  const float g2e = g2[e];
  float ssq = 0.f;
  #pragma unroll
  for (int j = 0; j < 4; ++j) {
    float s = val[j] * val[j];
    #pragma unroll
    for (int o = 1; o < 64; o <<= 1) s += __shfl_xor(s, o);
    const float rn = rsqrtf(s * (1.f / 64.f) + RMS_EPS);
    val[j] = val[j] * rn * g2e * 0.8f;
    ssq += val[j] * val[j];
  }
  // row rmsnorm over 1024 + residual
  #pragma unroll
  for (int o = 1; o < 64; o <<= 1) ssq += __shfl_xor(ssq, o);
  if (lane == 0) red[w] = ssq;
  __syncthreads();
  const float rn2 = rsqrtf((red[0] + red[1] + red[2] + red[3]) * (1.f / 1024.f) + RMS_EPS);
  #pragma unroll
  for (int j = 0; j < 4; ++j) {
    const int h = w + 4 * j;
    const int n = h * 64 + e;
    const float o = val[j] * rn2 * g3[n] + val[j];
    attnf[(size_t)m * 1024 + n] = o;
    attnb[(size_t)m * 1024 + n] = (bf16_t)o;
  }
}

extern "C" void kernel_launch(void* const* d_in, const int* in_sizes, int n_in,
                              void* d_out, int out_size, void* d_ws, size_t ws_size,
                              hipStream_t stream) {
  const float* x   = (const float*)d_in[0];
  const float* Wq  = (const float*)d_in[1];
  const float* bq  = (const float*)d_in[2];
  const float* Wk  = (const float*)d_in[3];
  const float* bk  = (const float*)d_in[4];
  const float* Wv  = (const float*)d_in[5];
  const float* bv  = (const float*)d_in[6];
  const float* lp  = (const float*)d_in[7];
  const float* g1  = (const float*)d_in[8];
  const float* g2  = (const float*)d_in[9];
  const float* g3  = (const float*)d_in[10];
  const float* Wf1 = (const float*)d_in[11];
  const float* bf1 = (const float*)d_in[12];
  const float* Wf2 = (const float*)d_in[13];
  const float* bf2 = (const float*)d_in[14];

  char* ws = (char*)d_ws;
  bf16_t* wqkv  = (bf16_t*)(ws + 0);           // 6,291,456 B  [3072][1024] bf16
  bf16_t* wf1b  = (bf16_t*)(ws + 6291456);     // 2,097,152 B
  bf16_t* wf2b  = (bf16_t*)(ws + 8388608);     // 2,097,152 B
  float*  bqkv  = (float*)(ws + 10485760);     // 12,288 B
  bf16_t* xn    = (bf16_t*)(ws + 10498048);    // 16,777,216 B [8192][1024] bf16
  bf16_t* qkv   = (bf16_t*)(ws + 27275264);    // 50,331,648 B [8192][3072] bf16
  float*  attnf = (float*)(ws + 77606912);     // 33,554,432 B [8192][1024] f32
  bf16_t* attnb = (bf16_t*)(ws + 111161344);   // 16,777,216 B
  bf16_t* hbuf  = (bf16_t*)(ws + 127938560);   // 16,777,216 B  (end 144,715,776)

  cast_bf16_1m<<<1024, 256, 0, stream>>>(Wq, wqkv);
  cast_bf16_1m<<<1024, 256, 0, stream>>>(Wk, wqkv + (1u << 20));
  cast_bf16_1m<<<1024, 256, 0, stream>>>(Wv, wqkv + (2u << 20));
  cast_bf16_1m<<<1024, 256, 0, stream>>>(Wf1, wf1b);
  cast_bf16_1m<<<1024, 256, 0, stream>>>(Wf2, wf2b);
  concat_bias<<<12, 256, 0, stream>>>(bq, bk, bv, bqkv);
  rmsnorm_x<<<8192, 256, 0, stream>>>(x, g1, xn);
  gemm_nt<0><<<1536, 256, 0, stream>>>(xn, wqkv, bqkv, nullptr, (void*)qkv, 8192, 3072, 1024);
  attn_pos<<<8192, 256, 0, stream>>>(qkv, lp, g2, g3, attnf, attnb);
  gemm_nt<1><<<512, 256, 0, stream>>>(attnb, wf1b, bf1, nullptr, (void*)hbuf, 8192, 1024, 1024);
  gemm_nt<2><<<512, 256, 0, stream>>>(hbuf, wf2b, bf2, attnf, d_out, 8192, 1024, 1024);
}

// Round 2
// 283.396 us; speedup vs baseline: 1.2009x; 1.2009x over previous
//
#include <hip/hip_runtime.h>
#include <cmath>

typedef __bf16 bf16_t;
typedef __attribute__((ext_vector_type(8))) __bf16 bf16x8;
typedef __attribute__((ext_vector_type(4))) __bf16 bf16x4;
typedef __attribute__((ext_vector_type(4))) float f32x4;

#define RMS_EPS 1.1920929e-07f
#define KV_SCALE 0.04419417382415922f   // 1/sqrt(512)

__device__ __forceinline__ void gload16(const void* g, void* l) {
  __builtin_amdgcn_global_load_lds((const __attribute__((address_space(1))) void*)g,
                                   (__attribute__((address_space(3))) void*)l, 16, 0, 0);
}

// ---------- fp32 -> bf16 cast, exactly 1M elements: grid 1024 x 256 ----------
__global__ __launch_bounds__(256) void cast_bf16_1m(const float* __restrict__ s,
                                                    bf16_t* __restrict__ d) {
  int i = (blockIdx.x * 256 + threadIdx.x) * 4;
  float4 v = *(const float4*)(s + i);
  bf16x4 o;
  o[0] = (bf16_t)v.x; o[1] = (bf16_t)v.y; o[2] = (bf16_t)v.z; o[3] = (bf16_t)v.w;
  *(bf16x4*)(d + i) = o;
}

__global__ void concat_bias(const float* __restrict__ bq, const float* __restrict__ bk,
                            const float* __restrict__ bv, float* __restrict__ dst) {
  int i = blockIdx.x * 256 + threadIdx.x;   // grid 12*256 = 3072
  float v;
  if (i < 1024) v = bq[i];
  else if (i < 2048) v = bk[i - 1024];
  else v = bv[i - 2048];
  dst[i] = v;
}

// ---------- RMSNorm(x, g1) -> bf16, one block per row of 1024 ----------
__global__ __launch_bounds__(256) void rmsnorm_x(const float* __restrict__ x,
                                                 const float* __restrict__ g,
                                                 bf16_t* __restrict__ xn) {
  const int m = blockIdx.x, t = threadIdx.x;
  const float4 v = ((const float4*)(x + (size_t)m * 1024))[t];
  float ss = v.x * v.x + v.y * v.y + v.z * v.z + v.w * v.w;
  #pragma unroll
  for (int o = 1; o < 64; o <<= 1) ss += __shfl_xor(ss, o);
  __shared__ float red[4];
  if ((t & 63) == 0) red[t >> 6] = ss;
  __syncthreads();
  const float r = rsqrtf((red[0] + red[1] + red[2] + red[3]) * (1.f / 1024.f) + RMS_EPS);
  const float4 gv = ((const float4*)g)[t];
  bf16x4 o;
  o[0] = (bf16_t)(v.x * r * gv.x); o[1] = (bf16_t)(v.y * r * gv.y);
  o[2] = (bf16_t)(v.z * r * gv.z); o[3] = (bf16_t)(v.w * r * gv.w);
  *(bf16x4*)(xn + (size_t)m * 1024 + t * 4) = o;
}

// ---------- NT GEMM: C[m,n] = sum_k A[m,k]*B[n,k], m97 structure ----------
// MODE 0: +bias -> bf16 out     (QKV, N=3072)
// MODE 1: +bias -> gelu -> bf16 (FFN1, N=1024)
// MODE 2: +bias +bf16 resid -> f32 (FFN2, N=1024)
template <int MODE>
__global__ __launch_bounds__(256) void gemm_nt(const bf16_t* __restrict__ A,
                                               const bf16_t* __restrict__ Bm,
                                               const float* __restrict__ bias,
                                               const bf16_t* __restrict__ residb,
                                               void* __restrict__ outp,
                                               int M, int N, int K) {
  __shared__ bf16_t As[128][32];
  __shared__ bf16_t Bs[128][32];
  const int t = threadIdx.x;
  const int lane = t & 63;
  const int w = t >> 6;
  const int wm = w >> 1, wn = w & 1;
  const int nTN = N >> 7;

  // bijective XCD swizzle (nwg % 8 == 0 for all our grids)
  const int nwg = gridDim.x;
  const int cpx = nwg >> 3;
  int bid = blockIdx.x;
  bid = (bid & 7) * cpx + (bid >> 3);
  const int tm = bid / nTN, tn = bid % nTN;

  const size_t rowA = (size_t)tm * 128;
  const size_t rowB = (size_t)tn * 128;
  const size_t sK = (size_t)K;

  f32x4 acc[4][4];
  #pragma unroll
  for (int i = 0; i < 4; ++i)
    #pragma unroll
    for (int j = 0; j < 4; ++j) acc[i][j] = (f32x4){0.f, 0.f, 0.f, 0.f};

  const int sr = lane >> 2;          // staging row within 16-row group
  const int sc = (lane & 3) << 3;    // staging col (elements)
  const int r16 = lane & 15;
  const int c8 = (lane >> 4) << 3;

  for (int k0 = 0; k0 < K; k0 += 32) {
    gload16(A  + (rowA +      w * 16 + sr) * sK + (k0 + sc), &As[w * 16][0]);
    gload16(A  + (rowA + 64 + w * 16 + sr) * sK + (k0 + sc), &As[64 + w * 16][0]);
    gload16(Bm + (rowB +      w * 16 + sr) * sK + (k0 + sc), &Bs[w * 16][0]);
    gload16(Bm + (rowB + 64 + w * 16 + sr) * sK + (k0 + sc), &Bs[64 + w * 16][0]);
    __syncthreads();

    bf16x8 a[4], b[4];
    #pragma unroll
    for (int i = 0; i < 4; ++i) {
      a[i] = *(const bf16x8*)&As[wm * 64 + i * 16 + r16][c8];
      b[i] = *(const bf16x8*)&Bs[wn * 64 + i * 16 + r16][c8];
    }
    #pragma unroll
    for (int i = 0; i < 4; ++i)
      #pragma unroll
      for (int j = 0; j < 4; ++j)
        acc[i][j] = __builtin_amdgcn_mfma_f32_16x16x32_bf16(a[i], b[j], acc[i][j], 0, 0, 0);
    __syncthreads();
  }

  // epilogue: C/D layout col = lane&15, row = (lane>>4)*4 + reg
  const int hi4 = (lane >> 4) * 4;
  #pragma unroll
  for (int i = 0; i < 4; ++i) {
    #pragma unroll
    for (int j = 0; j < 4; ++j) {
      const int gc = tn * 128 + wn * 64 + j * 16 + r16;
      const float bv = bias[gc];
      #pragma unroll
      for (int r = 0; r < 4; ++r) {
        const int gr = tm * 128 + wm * 64 + i * 16 + hi4 + r;
        float v = acc[i][j][r] + bv;
        if constexpr (MODE == 0) {
          ((bf16_t*)outp)[(size_t)gr * N + gc] = (bf16_t)v;
        } else if constexpr (MODE == 1) {
          v = 0.5f * v * (1.0f + erff(v * 0.70710678118654752f));
          ((bf16_t*)outp)[(size_t)gr * N + gc] = (bf16_t)v;
        } else {
          v += (float)residb[(size_t)gr * N + gc];
          ((float*)outp)[(size_t)gr * N + gc] = v;
        }
      }
    }
  }
}

// ---------- fused differential linear attention, one wave per position ----------
// attn = SCALE*(phiQ1 @ phiK1^T - lambda * phiQ2 @ phiK2^T) @ V, then
// 0.8*rmsnorm(.,g2) per head, then rmsnorm(.,g3)+resid over 1024. Out: bf16.
__global__ __launch_bounds__(256) void attn_fused(const bf16_t* __restrict__ qkv,
                                                  const float* __restrict__ lp,
                                                  const float* __restrict__ g2,
                                                  const float* __restrict__ g3,
                                                  bf16_t* __restrict__ attnb) {
  __shared__ __align__(16) char lds[4][6656];
  const int t = threadIdx.x;
  const int lane = t & 63;
  const int w = t >> 6;
  const int m = blockIdx.x * 4 + w;
  char* const sQ  = lds[w];          // [16 h][64 d] bf16, 128B rows, swz ((h&7)<<4)
  char* const sK  = lds[w] + 2048;   // same layout
  char* const sVt = lds[w] + 4096;   // [64 e][16 h'] bf16, 32B rows, swz ((e&1)<<4)
  char* const sSb = lds[w] + 6144;   // [16 h][16 h'] bf16, 32B rows, swz ((h&1)<<4)

  const float lmbda = __expf(lp[0] * lp[1]) - __expf(lp[2] * lp[3]) + 0.2f;
  const int l7 = lane & 7, l8 = lane >> 3;
  const bf16x8* src = (const bf16x8*)(qkv + (size_t)m * 3072);

  // stage Q (elu, fold SCALE / -lambda*SCALE per d-half), K (elu), V^T
  const float qsc = (l7 < 4) ? KV_SCALE : -lmbda * KV_SCALE;
  #pragma unroll
  for (int c = 0; c < 2; ++c) {
    bf16x8 v = src[c * 64 + lane];
    const int h = c * 8 + l8;
    bf16x8 o;
    #pragma unroll
    for (int i = 0; i < 8; ++i) {
      float f = (float)v[i];
      f = f > 0.f ? f : __expf(f) - 1.f;
      o[i] = (bf16_t)(f * qsc);
    }
    *(bf16x8*)(sQ + ((h * 128 + 16 * l7) ^ ((h & 7) << 4))) = o;
  }
  #pragma unroll
  for (int c = 2; c < 4; ++c) {
    bf16x8 v = src[c * 64 + lane];
    const int h = (c - 2) * 8 + l8;
    bf16x8 o;
    #pragma unroll
    for (int i = 0; i < 8; ++i) {
      float f = (float)v[i];
      f = f > 0.f ? f : __expf(f) - 1.f;
      o[i] = (bf16_t)f;
    }
    *(bf16x8*)(sK + ((h * 128 + 16 * l7) ^ ((h & 7) << 4))) = o;
  }
  #pragma unroll
  for (int c = 4; c < 6; ++c) {
    bf16x8 v = src[c * 64 + lane];
    const int h = (c - 4) * 8 + l8;
    #pragma unroll
    for (int i = 0; i < 8; ++i) {
      const int e = 8 * l7 + i;
      *(bf16_t*)(sVt + ((e * 32 + h * 2) ^ ((e & 1) << 4))) = v[i];
    }
  }

  // S = Qtilde @ K^T over d=64 (two chained 16x16x32 mfmas)
  const int r16 = lane & 15, g4 = lane >> 4;
  f32x4 accS = {};
  {
    const int ra = r16 * 128;
    const int sw = (r16 & 7) << 4;
    bf16x8 a0 = *(const bf16x8*)(sQ + ((ra + 16 * g4) ^ sw));
    bf16x8 b0 = *(const bf16x8*)(sK + ((ra + 16 * g4) ^ sw));
    bf16x8 a1 = *(const bf16x8*)(sQ + ((ra + 64 + 16 * g4) ^ sw));
    bf16x8 b1 = *(const bf16x8*)(sK + ((ra + 64 + 16 * g4) ^ sw));
    accS = __builtin_amdgcn_mfma_f32_16x16x32_bf16(a0, b0, accS, 0, 0, 0);
    accS = __builtin_amdgcn_mfma_f32_16x16x32_bf16(a1, b1, accS, 0, 0, 0);
  }

  // Sc -> bf16 in LDS (transpose via LDS round-trip for the a-frag)
  #pragma unroll
  for (int r = 0; r < 4; ++r) {
    const int h = g4 * 4 + r;
    *(bf16_t*)(sSb + ((h * 32 + 2 * r16) ^ ((h & 1) << 4))) = (bf16_t)accS[r];
  }

  // attn = Sc @ V: 16x16x32 mfma with K=16 zero-padded in registers
  bf16x8 zf = {};
  bf16x8 aS = zf;
  if (lane < 32) aS = *(const bf16x8*)(sSb + ((r16 * 32 + 16 * g4) ^ ((r16 & 1) << 4)));
  f32x4 accA[4];
  #pragma unroll
  for (int j = 0; j < 4; ++j) {
    bf16x8 bV = zf;
    if (lane < 32) {
      const int row = j * 16 + r16;
      bV = *(const bf16x8*)(sVt + ((row * 32 + 16 * g4) ^ ((row & 1) << 4)));
    }
    f32x4 z4 = {};
    accA[j] = __builtin_amdgcn_mfma_f32_16x16x32_bf16(aS, bV, z4, 0, 0, 0);
  }

  // group rmsnorm over e (per h), * g2 * 0.8
  float rnh[4];
  #pragma unroll
  for (int r = 0; r < 4; ++r) {
    float s = 0.f;
    #pragma unroll
    for (int j = 0; j < 4; ++j) s += accA[j][r] * accA[j][r];
    #pragma unroll
    for (int o = 1; o < 16; o <<= 1) s += __shfl_xor(s, o);
    rnh[r] = rsqrtf(s * (1.f / 64.f) + RMS_EPS);
  }
  float g2v[4];
  #pragma unroll
  for (int j = 0; j < 4; ++j) g2v[j] = g2[j * 16 + r16];
  float val[4][4];
  float tot = 0.f;
  #pragma unroll
  for (int j = 0; j < 4; ++j)
    #pragma unroll
    for (int r = 0; r < 4; ++r) {
      const float vv = accA[j][r] * rnh[r] * g2v[j] * 0.8f;
      val[j][r] = vv;
      tot += vv * vv;
    }
  #pragma unroll
  for (int o = 1; o < 64; o <<= 1) tot += __shfl_xor(tot, o);
  const float rn2 = rsqrtf(tot * (1.f / 1024.f) + RMS_EPS);

  bf16_t* dst = attnb + (size_t)m * 1024;
  #pragma unroll
  for (int j = 0; j < 4; ++j)
    #pragma unroll
    for (int r = 0; r < 4; ++r) {
      const int n = (g4 * 4 + r) * 64 + j * 16 + r16;
      const float ov = val[j][r] * rn2 * g3[n] + val[j][r];
      dst[n] = (bf16_t)ov;
    }
}

extern "C" void kernel_launch(void* const* d_in, const int* in_sizes, int n_in,
                              void* d_out, int out_size, void* d_ws, size_t ws_size,
                              hipStream_t stream) {
  const float* x   = (const float*)d_in[0];
  const float* Wq  = (const float*)d_in[1];
  const float* bq  = (const float*)d_in[2];
  const float* Wk  = (const float*)d_in[3];
  const float* bk  = (const float*)d_in[4];
  const float* Wv  = (const float*)d_in[5];
  const float* bv  = (const float*)d_in[6];
  const float* lp  = (const float*)d_in[7];
  const float* g1  = (const float*)d_in[8];
  const float* g2  = (const float*)d_in[9];
  const float* g3  = (const float*)d_in[10];
  const float* Wf1 = (const float*)d_in[11];
  const float* bf1 = (const float*)d_in[12];
  const float* Wf2 = (const float*)d_in[13];
  const float* bf2 = (const float*)d_in[14];

  char* ws = (char*)d_ws;
  bf16_t* wqkv  = (bf16_t*)(ws + 0);           // 6,291,456 B  [3072][1024] bf16
  bf16_t* wf1b  = (bf16_t*)(ws + 6291456);     // 2,097,152 B
  bf16_t* wf2b  = (bf16_t*)(ws + 8388608);     // 2,097,152 B
  float*  bqkv  = (float*)(ws + 10485760);     // 12,288 B
  bf16_t* xn    = (bf16_t*)(ws + 10498048);    // 16,777,216 B [8192][1024] bf16
  bf16_t* qkv   = (bf16_t*)(ws + 27275264);    // 50,331,648 B [8192][3072] bf16
  bf16_t* attnb = (bf16_t*)(ws + 77606912);    // 16,777,216 B [8192][1024] bf16
  bf16_t* hbuf  = (bf16_t*)(ws + 94384128);    // 16,777,216 B (end 111,161,344)

  cast_bf16_1m<<<1024, 256, 0, stream>>>(Wq, wqkv);
  cast_bf16_1m<<<1024, 256, 0, stream>>>(Wk, wqkv + (1u << 20));
  cast_bf16_1m<<<1024, 256, 0, stream>>>(Wv, wqkv + (2u << 20));
  cast_bf16_1m<<<1024, 256, 0, stream>>>(Wf1, wf1b);
  cast_bf16_1m<<<1024, 256, 0, stream>>>(Wf2, wf2b);
  concat_bias<<<12, 256, 0, stream>>>(bq, bk, bv, bqkv);
  rmsnorm_x<<<8192, 256, 0, stream>>>(x, g1, xn);
  gemm_nt<0><<<1536, 256, 0, stream>>>(xn, wqkv, bqkv, nullptr, (void*)qkv, 8192, 3072, 1024);
  attn_fused<<<2048, 256, 0, stream>>>(qkv, lp, g2, g3, attnb);
  gemm_nt<1><<<512, 256, 0, stream>>>(attnb, wf1b, bf1, nullptr, (void*)hbuf, 8192, 1024, 1024);
  gemm_nt<2><<<512, 256, 0, stream>>>(hbuf, wf2b, bf2, attnb, d_out, 8192, 1024, 1024);
}